// Round 6
// baseline (370.850 us; speedup 1.0000x reference)
//
#include <hip/hip_runtime.h>

#define NN    50000   // nodes
#define NHE   50000   // hyperedges
#define NEDGE 320000  // incidence pairs
#define DD    256     // feature dim

#define SB    1024                    // scan elements per block
#define NBLK  ((NN + SB - 1) / SB)    // blocks per segment (NN == NHE)

typedef float f32x4 __attribute__((ext_vector_type(4)));
typedef short short8 __attribute__((ext_vector_type(8)));

// ---- bf16 helpers (RTNE) ----
static __device__ __forceinline__ unsigned short f2b(float f) {
    union { float f; unsigned u; } c; c.f = f;
    unsigned u = c.u;
    u += 0x7fffu + ((u >> 16) & 1u);
    return (unsigned short)(u >> 16);
}
static __device__ __forceinline__ float b2f_lo(unsigned v) {
    union { unsigned u; float f; } c; c.u = v << 16; return c.f;
}
static __device__ __forceinline__ float b2f_hi(unsigned v) {
    union { unsigned u; float f; } c; c.u = v & 0xffff0000u; return c.f;
}
static __device__ __forceinline__ unsigned pack2(float a, float b) {
    return (unsigned)f2b(a) | ((unsigned)f2b(b) << 16);
}

// ---------------- CSR build ----------------
__global__ __launch_bounds__(256) void k_count(const int* __restrict__ src,
                                               const int* __restrict__ he,
                                               int* __restrict__ cnt_n,
                                               int* __restrict__ cnt_e) {
    int e = blockIdx.x * 256 + threadIdx.x;
    if (e >= NEDGE) return;
    atomicAdd(&cnt_n[src[e]], 1);
    atomicAdd(&cnt_e[he[e]], 1);
}

__global__ __launch_bounds__(256) void k_scan_a(const int* __restrict__ cnt_n,
                                                const int* __restrict__ cnt_e,
                                                int* __restrict__ bsum) {
    int b   = blockIdx.x;            // 0 .. 2*NBLK-1
    int seg = b / NBLK, lb = b % NBLK;
    const int* cnt = seg ? cnt_e : cnt_n;
    int t = threadIdx.x;
    int idx = lb * SB + t * 4;
    int s = 0;
#pragma unroll
    for (int j = 0; j < 4; ++j)
        if (idx + j < NN) s += cnt[idx + j];
    __shared__ int red[256];
    red[t] = s;
    __syncthreads();
    for (int o = 128; o > 0; o >>= 1) {
        if (t < o) red[t] += red[t + o];
        __syncthreads();
    }
    if (t == 0) bsum[b] = red[0];
}

__global__ __launch_bounds__(64) void k_scan_b(const int* __restrict__ bsum,
                                               int* __restrict__ bbase) {
    if (threadIdx.x == 0) {
        int r = 0;
        for (int i = 0; i < NBLK; ++i) { bbase[i] = r; r += bsum[i]; }
        bbase[2 * NBLK] = r;
        r = 0;
        for (int i = NBLK; i < 2 * NBLK; ++i) { bbase[i] = r; r += bsum[i]; }
        bbase[2 * NBLK + 1] = r;
    }
}

__global__ __launch_bounds__(256) void k_scan_c(const int* __restrict__ cnt_n,
                                                const int* __restrict__ cnt_e,
                                                const int* __restrict__ bbase,
                                                int* __restrict__ off_n,
                                                int* __restrict__ off_e) {
    int b   = blockIdx.x;
    int seg = b / NBLK, lb = b % NBLK;
    const int* cnt = seg ? cnt_e : cnt_n;
    int* off = seg ? off_e : off_n;
    int t = threadIdx.x;
    int idx = lb * SB + t * 4;
    int v[4];
    int tsum = 0;
#pragma unroll
    for (int j = 0; j < 4; ++j) {
        v[j] = (idx + j < NN) ? cnt[idx + j] : 0;
        tsum += v[j];
    }
    __shared__ int sc[256];
    sc[t] = tsum;
    __syncthreads();
    for (int o = 1; o < 256; o <<= 1) {
        int val = (t >= o) ? sc[t - o] : 0;
        __syncthreads();
        sc[t] += val;
        __syncthreads();
    }
    int p = bbase[b] + sc[t] - tsum;
#pragma unroll
    for (int j = 0; j < 4; ++j) {
        if (idx + j < NN) off[idx + j] = p;
        p += v[j];
    }
    if (b == 0 && t == 0) off_n[NN] = bbase[2 * NBLK];
    if (b == NBLK && t == 0) off_e[NHE] = bbase[2 * NBLK + 1];
}

__global__ __launch_bounds__(256) void k_fill(const int* __restrict__ src,
                                              const int* __restrict__ he,
                                              const int* __restrict__ off_n,
                                              const int* __restrict__ off_e,
                                              int* __restrict__ cur_n,
                                              int* __restrict__ cur_e,
                                              int* __restrict__ adj_n,
                                              int* __restrict__ adj_e) {
    int e = blockIdx.x * 256 + threadIdx.x;
    if (e >= NEDGE) return;
    int s = src[e], h = he[e];
    int pn = off_n[s] + atomicAdd(&cur_n[s], 1);
    adj_n[pn] = h;
    int pe = off_e[h] + atomicAdd(&cur_e[h], 1);
    adj_e[pe] = s;
}

// ---------------- weights fp32 -> bf16 ----------------
__global__ __launch_bounds__(256) void k_cvt_w(const float* __restrict__ w1,
                                               const float* __restrict__ w2,
                                               unsigned short* __restrict__ o1,
                                               unsigned short* __restrict__ o2) {
    int t = blockIdx.x * 256 + threadIdx.x;
    const int n4 = DD * DD / 4;
    const float* s = (t < n4) ? w1 : w2;
    unsigned short* d = (t < n4) ? o1 : o2;
    int i = (t < n4) ? t : t - n4;
    float4 v = ((const float4*)s)[i];
    uint2 o;
    o.x = pack2(v.x, v.y);
    o.y = pack2(v.z, v.w);
    ((uint2*)d)[i] = o;
}

// ---------------- bf16 MFMA GEMM, double-buffered LDS + register prefetch ----
// C[m,n] = sum_k A[m,k]*W[n,k]; tile 128x128, BK=32, K=256 (8 steps, unrolled).
template <bool A32>
__global__ __launch_bounds__(256) void k_gemm_bf16(const void* __restrict__ Av,
                                                   const unsigned short* __restrict__ Wb,
                                                   unsigned short* __restrict__ Cb, int M) {
    __shared__ __align__(16) unsigned short As[2][128 * 32];
    __shared__ __align__(16) unsigned short Bs[2][128 * 32];
    const int t    = threadIdx.x;
    const int m0   = blockIdx.x * 128;
    const int n0   = blockIdx.y * 128;
    const int lane = t & 63;
    const int wave = t >> 6;
    const int wm   = (wave >> 1) * 64;
    const int wn   = (wave & 1) * 64;
    const int fr   = lane & 15;
    const int fq   = lane >> 4;

    f32x4 acc[4][4] = {};

    const int sr = t >> 2;   // staging row 0..63 (and +64)
    const int ss = t & 3;    // 8-elem segment

    uint4 pa[2], pb[2];
    // ---- load of K-step k0 into regs ----
    auto loadT = [&](int k0, uint4* ra, uint4* rb) {
#pragma unroll
        for (int i = 0; i < 2; ++i) {
            int r  = sr + i * 64;
            int gm = m0 + r;
            uint4 av = make_uint4(0u, 0u, 0u, 0u);
            if (gm < M) {
                if (A32) {
                    const float* p = (const float*)Av + (size_t)gm * DD + k0 + ss * 8;
                    float4 f0 = *(const float4*)p;
                    float4 f1 = *(const float4*)(p + 4);
                    av.x = pack2(f0.x, f0.y);
                    av.y = pack2(f0.z, f0.w);
                    av.z = pack2(f1.x, f1.y);
                    av.w = pack2(f1.z, f1.w);
                } else {
                    av = *(const uint4*)((const unsigned short*)Av + (size_t)gm * DD + k0 + ss * 8);
                }
            }
            ra[i] = av;
            rb[i] = *(const uint4*)(Wb + (size_t)(n0 + r) * DD + k0 + ss * 8);
        }
    };
    auto storeT = [&](int buf, const uint4* ra, const uint4* rb) {
#pragma unroll
        for (int i = 0; i < 2; ++i) {
            int r = sr + i * 64;
            *(uint4*)(As[buf] + r * 32 + ((ss ^ (r & 3)) * 8)) = ra[i];
            *(uint4*)(Bs[buf] + r * 32 + ((ss ^ (r & 3)) * 8)) = rb[i];
        }
    };

    loadT(0, pa, pb);
    storeT(0, pa, pb);

#pragma unroll
    for (int kk = 0; kk < 8; ++kk) {
        __syncthreads();
        uint4 na[2], nb[2];
        if (kk < 7) loadT((kk + 1) * 32, na, nb);   // prefetch next K-step

        const int buf = kk & 1;
        short8 af[4], bf[4];
#pragma unroll
        for (int mt = 0; mt < 4; ++mt) {
            int r = wm + mt * 16 + fr;
            af[mt] = *(const short8*)(As[buf] + r * 32 + ((fq ^ (r & 3)) * 8));
        }
#pragma unroll
        for (int nt = 0; nt < 4; ++nt) {
            int r = wn + nt * 16 + fr;
            bf[nt] = *(const short8*)(Bs[buf] + r * 32 + ((fq ^ (r & 3)) * 8));
        }
#pragma unroll
        for (int mt = 0; mt < 4; ++mt)
#pragma unroll
            for (int nt = 0; nt < 4; ++nt)
                acc[mt][nt] = __builtin_amdgcn_mfma_f32_16x16x32_bf16(af[mt], bf[nt],
                                                                      acc[mt][nt], 0, 0, 0);
        if (kk < 7) storeT(1 - buf, na, nb);        // write into the other buffer
    }

    // C/D layout: col = lane&15, row = quad*4 + reg
#pragma unroll
    for (int mt = 0; mt < 4; ++mt) {
#pragma unroll
        for (int i = 0; i < 4; ++i) {
            int gm = m0 + wm + mt * 16 + fq * 4 + i;
            if (gm >= M) continue;
#pragma unroll
            for (int nt = 0; nt < 4; ++nt) {
                int gn = n0 + wn + nt * 16 + fr;
                Cb[(size_t)gm * DD + gn] = f2b(acc[mt][nt][i]);
            }
        }
    }
}

// ---------------- gather core: 32 lanes per row, uint4 (8 bf16) per lane ------
// unroll-4 neighbor batches -> 4x16B outstanding per lane; branches are
// half-wave-uniform; clamped duplicate indices hit L1 (~free).
static __device__ __forceinline__ void acc8(float* a, uint4 v) {
    a[0] += b2f_lo(v.x); a[1] += b2f_hi(v.x);
    a[2] += b2f_lo(v.y); a[3] += b2f_hi(v.y);
    a[4] += b2f_lo(v.z); a[5] += b2f_hi(v.z);
    a[6] += b2f_lo(v.w); a[7] += b2f_hi(v.w);
}
static __device__ __forceinline__ void gather8(const unsigned short* __restrict__ srcb,
                                               const int* __restrict__ adj,
                                               int b, int e, int sl, float* a) {
#pragma unroll
    for (int i = 0; i < 8; ++i) a[i] = 0.f;
    for (int i = b; i < e; i += 4) {
        int g0 = adj[i];
        int g1 = (i + 1 < e) ? adj[i + 1] : g0;
        int g2 = (i + 2 < e) ? adj[i + 2] : g0;
        int g3 = (i + 3 < e) ? adj[i + 3] : g0;
        uint4 v0 = *(const uint4*)(srcb + (size_t)g0 * DD + sl * 8);
        uint4 v1 = *(const uint4*)(srcb + (size_t)g1 * DD + sl * 8);
        uint4 v2 = *(const uint4*)(srcb + (size_t)g2 * DD + sl * 8);
        uint4 v3 = *(const uint4*)(srcb + (size_t)g3 * DD + sl * 8);
        acc8(a, v0);
        if (i + 1 < e) acc8(a, v1);
        if (i + 2 < e) acc8(a, v2);
        if (i + 3 < e) acc8(a, v3);
    }
}

__global__ __launch_bounds__(256) void k_gather_edge_b(const unsigned short* __restrict__ xw,
                                                       unsigned short* __restrict__ ef,
                                                       const int* __restrict__ off,
                                                       const int* __restrict__ adj) {
    int tid = blockIdx.x * 256 + threadIdx.x;
    int w = tid >> 5;           // one 32-lane half-wave per row
    int sl = tid & 31;
    if (w >= NHE) return;
    int b = off[w], e = off[w + 1];
    float a[8];
    gather8(xw, adj, b, e, sl, a);
    float sc = (e > b) ? 1.f / (float)(e - b) : 0.f;
    uint4 o;
    o.x = pack2(a[0] * sc, a[1] * sc);
    o.y = pack2(a[2] * sc, a[3] * sc);
    o.z = pack2(a[4] * sc, a[5] * sc);
    o.w = pack2(a[6] * sc, a[7] * sc);
    *(uint4*)(ef + (size_t)w * DD + sl * 8) = o;
}

__global__ __launch_bounds__(256) void k_gather_node_mid_b(const unsigned short* __restrict__ ef,
                                                           unsigned short* __restrict__ h,
                                                           const int* __restrict__ off,
                                                           const int* __restrict__ adj,
                                                           const float* __restrict__ bias,
                                                           const float* __restrict__ aP) {
    int tid = blockIdx.x * 256 + threadIdx.x;
    int w = tid >> 5;
    int sl = tid & 31;
    if (w >= NN) return;
    int b = off[w], e = off[w + 1];
    float a[8];
    gather8(ef, adj, b, e, sl, a);
    float sc = (e > b) ? 1.f / (float)(e - b) : 0.f;
    float al = *aP;
    float4 bb0 = ((const float4*)bias)[sl * 2];
    float4 bb1 = ((const float4*)bias)[sl * 2 + 1];
    float r[8];
    r[0] = a[0] * sc + bb0.x; r[1] = a[1] * sc + bb0.y;
    r[2] = a[2] * sc + bb0.z; r[3] = a[3] * sc + bb0.w;
    r[4] = a[4] * sc + bb1.x; r[5] = a[5] * sc + bb1.y;
    r[6] = a[6] * sc + bb1.z; r[7] = a[7] * sc + bb1.w;
#pragma unroll
    for (int i = 0; i < 8; ++i) r[i] = (r[i] >= 0.f) ? r[i] : al * r[i];
    uint4 o;
    o.x = pack2(r[0], r[1]);
    o.y = pack2(r[2], r[3]);
    o.z = pack2(r[4], r[5]);
    o.w = pack2(r[6], r[7]);
    *(uint4*)(h + (size_t)w * DD + sl * 8) = o;
}

__global__ __launch_bounds__(256) void k_gather_node_final_b(const unsigned short* __restrict__ ef,
                                                             const float* __restrict__ x,
                                                             float* __restrict__ out,
                                                             const int* __restrict__ off,
                                                             const int* __restrict__ adj,
                                                             const float* __restrict__ bias,
                                                             const float* __restrict__ aP) {
    int tid = blockIdx.x * 256 + threadIdx.x;
    int w = tid >> 5;
    int sl = tid & 31;
    if (w >= NN) return;
    int b = off[w], e = off[w + 1];
    float a[8];
    gather8(ef, adj, b, e, sl, a);
    float sc = (e > b) ? 1.f / (float)(e - b) : 0.f;
    float al = *aP;
    float4 bb0 = ((const float4*)bias)[sl * 2];
    float4 bb1 = ((const float4*)bias)[sl * 2 + 1];
    const float* xp = x + (size_t)w * DD + sl * 8;
    float4 xv0 = *(const float4*)xp;
    float4 xv1 = *(const float4*)(xp + 4);
    float r[8];
    r[0] = a[0] * sc + bb0.x + xv0.x; r[1] = a[1] * sc + bb0.y + xv0.y;
    r[2] = a[2] * sc + bb0.z + xv0.z; r[3] = a[3] * sc + bb0.w + xv0.w;
    r[4] = a[4] * sc + bb1.x + xv1.x; r[5] = a[5] * sc + bb1.y + xv1.y;
    r[6] = a[6] * sc + bb1.z + xv1.z; r[7] = a[7] * sc + bb1.w + xv1.w;
#pragma unroll
    for (int i = 0; i < 8; ++i) r[i] = (r[i] >= 0.f) ? r[i] : al * r[i];
    float* op = out + (size_t)w * DD + sl * 8;
    *(float4*)op = make_float4(r[0], r[1], r[2], r[3]);
    *(float4*)(op + 4) = make_float4(r[4], r[5], r[6], r[7]);
}

extern "C" void kernel_launch(void* const* d_in, const int* in_sizes, int n_in,
                              void* d_out, int out_size, void* d_ws, size_t ws_size,
                              hipStream_t stream) {
    const float* x       = (const float*)d_in[0];
    const float* W1      = (const float*)d_in[1];
    const float* b1      = (const float*)d_in[2];
    const float* W2      = (const float*)d_in[3];
    const float* b2      = (const float*)d_in[4];
    const float* prelu_a = (const float*)d_in[5];
    const int*   hei     = (const int*)d_in[6];
    const int* idx_src = hei;          // hei[0,:] node indices
    const int* idx_he  = hei + NEDGE;  // hei[1,:] hyperedge indices

    float* out = (float*)d_out;
    unsigned short* B1 = (unsigned short*)d_ws;           // [NN*DD] bf16
    unsigned short* B2 = B1 + (size_t)NN * DD;            // [NN*DD] bf16
    int* off_n = (int*)(B2 + (size_t)NN * DD);            // NN+1
    int* off_e = off_n + NN + 1;                          // NHE+1
    int* cur_n = off_e + NHE + 1;                         // NN (counts)
    int* cur_e = cur_n + NN;                              // NHE
    int* adj_n = cur_e + NHE;                             // NEDGE
    int* adj_e = adj_n + NEDGE;                           // NEDGE
    int* bsum  = adj_e + NEDGE;                           // 2*NBLK
    int* bbase = bsum + 2 * NBLK;                         // 2*NBLK + 2
    // d_out doubles as bf16 weight storage until the final kernel
    unsigned short* w1b = (unsigned short*)d_out;         // [DD*DD]
    unsigned short* w2b = w1b + DD * DD;                  // [DD*DD]

    const int eblocks = (NEDGE + 255) / 256;
    const int gblocks = (NN * 32 + 255) / 256;            // 32 lanes per row
    dim3 ggrid((NN + 127) / 128, DD / 128);

    // ---- CSR build (parallel scan) ----
    hipMemsetAsync(cur_n, 0, sizeof(int) * (NN + NHE), stream);
    k_count<<<eblocks, 256, 0, stream>>>(idx_src, idx_he, cur_n, cur_e);
    k_scan_a<<<2 * NBLK, 256, 0, stream>>>(cur_n, cur_e, bsum);
    k_scan_b<<<1, 64, 0, stream>>>(bsum, bbase);
    k_scan_c<<<2 * NBLK, 256, 0, stream>>>(cur_n, cur_e, bbase, off_n, off_e);
    hipMemsetAsync(cur_n, 0, sizeof(int) * (NN + NHE), stream);
    k_fill<<<eblocks, 256, 0, stream>>>(idx_src, idx_he, off_n, off_e,
                                        cur_n, cur_e, adj_n, adj_e);

    // ---- weight conversions (x conversion fused into GEMM1) ----
    k_cvt_w<<<(2 * DD * DD / 4 + 255) / 256, 256, 0, stream>>>(W1, W2, w1b, w2b);

    // ---- layer 1 ----
    k_gemm_bf16<true><<<ggrid, 256, 0, stream>>>((const void*)x, w1b, B1, NN);   // B1 = bf16(x@W1^T)
    k_gather_edge_b<<<gblocks, 256, 0, stream>>>(B1, B2, off_e, adj_e);          // B2 = ef1
    k_gather_node_mid_b<<<gblocks, 256, 0, stream>>>(B2, B1, off_n, adj_n, b1, prelu_a); // B1 = h1

    // ---- layer 2 ----
    k_gemm_bf16<false><<<ggrid, 256, 0, stream>>>((const void*)B1, w2b, B2, NN); // B2 = bf16(h1@W2^T)
    k_gather_edge_b<<<gblocks, 256, 0, stream>>>(B2, B1, off_e, adj_e);          // B1 = ef2
    k_gather_node_final_b<<<gblocks, 256, 0, stream>>>(B1, x, out, off_n, adj_n, b2, prelu_a);
}

// Round 7
// 332.761 us; speedup vs baseline: 1.1145x; 1.1145x over previous
//
#include <hip/hip_runtime.h>

#define NN    50000   // nodes
#define NHE   50000   // hyperedges
#define NEDGE 320000  // incidence pairs
#define DD    256     // feature dim

#define SB    1024                    // scan elements per block
#define NBLK  ((NN + SB - 1) / SB)    // blocks per segment (NN == NHE)

typedef float f32x4 __attribute__((ext_vector_type(4)));
typedef short short8 __attribute__((ext_vector_type(8)));

// ---- bf16 helpers (RTNE) ----
static __device__ __forceinline__ unsigned short f2b(float f) {
    union { float f; unsigned u; } c; c.f = f;
    unsigned u = c.u;
    u += 0x7fffu + ((u >> 16) & 1u);
    return (unsigned short)(u >> 16);
}
static __device__ __forceinline__ float b2f_lo(unsigned v) {
    union { unsigned u; float f; } c; c.u = v << 16; return c.f;
}
static __device__ __forceinline__ float b2f_hi(unsigned v) {
    union { unsigned u; float f; } c; c.u = v & 0xffff0000u; return c.f;
}
static __device__ __forceinline__ unsigned pack2(float a, float b) {
    return (unsigned)f2b(a) | ((unsigned)f2b(b) << 16);
}

// ---------------- CSR build ----------------
__global__ __launch_bounds__(256) void k_count(const int* __restrict__ src,
                                               const int* __restrict__ he,
                                               int* __restrict__ cnt_n,
                                               int* __restrict__ cnt_e) {
    int e = blockIdx.x * 256 + threadIdx.x;
    if (e >= NEDGE) return;
    atomicAdd(&cnt_n[src[e]], 1);
    atomicAdd(&cnt_e[he[e]], 1);
}

__global__ __launch_bounds__(256) void k_scan_a(const int* __restrict__ cnt_n,
                                                const int* __restrict__ cnt_e,
                                                int* __restrict__ bsum) {
    int b   = blockIdx.x;            // 0 .. 2*NBLK-1
    int seg = b / NBLK, lb = b % NBLK;
    const int* cnt = seg ? cnt_e : cnt_n;
    int t = threadIdx.x;
    int idx = lb * SB + t * 4;
    int s = 0;
#pragma unroll
    for (int j = 0; j < 4; ++j)
        if (idx + j < NN) s += cnt[idx + j];
    __shared__ int red[256];
    red[t] = s;
    __syncthreads();
    for (int o = 128; o > 0; o >>= 1) {
        if (t < o) red[t] += red[t + o];
        __syncthreads();
    }
    if (t == 0) bsum[b] = red[0];
}

__global__ __launch_bounds__(64) void k_scan_b(const int* __restrict__ bsum,
                                               int* __restrict__ bbase) {
    if (threadIdx.x == 0) {
        int r = 0;
        for (int i = 0; i < NBLK; ++i) { bbase[i] = r; r += bsum[i]; }
        bbase[2 * NBLK] = r;
        r = 0;
        for (int i = NBLK; i < 2 * NBLK; ++i) { bbase[i] = r; r += bsum[i]; }
        bbase[2 * NBLK + 1] = r;
    }
}

__global__ __launch_bounds__(256) void k_scan_c(const int* __restrict__ cnt_n,
                                                const int* __restrict__ cnt_e,
                                                const int* __restrict__ bbase,
                                                int* __restrict__ off_n,
                                                int* __restrict__ off_e) {
    int b   = blockIdx.x;
    int seg = b / NBLK, lb = b % NBLK;
    const int* cnt = seg ? cnt_e : cnt_n;
    int* off = seg ? off_e : off_n;
    int t = threadIdx.x;
    int idx = lb * SB + t * 4;
    int v[4];
    int tsum = 0;
#pragma unroll
    for (int j = 0; j < 4; ++j) {
        v[j] = (idx + j < NN) ? cnt[idx + j] : 0;
        tsum += v[j];
    }
    __shared__ int sc[256];
    sc[t] = tsum;
    __syncthreads();
    for (int o = 1; o < 256; o <<= 1) {
        int val = (t >= o) ? sc[t - o] : 0;
        __syncthreads();
        sc[t] += val;
        __syncthreads();
    }
    int p = bbase[b] + sc[t] - tsum;
#pragma unroll
    for (int j = 0; j < 4; ++j) {
        if (idx + j < NN) off[idx + j] = p;
        p += v[j];
    }
    if (b == 0 && t == 0) off_n[NN] = bbase[2 * NBLK];
    if (b == NBLK && t == 0) off_e[NHE] = bbase[2 * NBLK + 1];
}

__global__ __launch_bounds__(256) void k_fill(const int* __restrict__ src,
                                              const int* __restrict__ he,
                                              const int* __restrict__ off_n,
                                              const int* __restrict__ off_e,
                                              int* __restrict__ cur_n,
                                              int* __restrict__ cur_e,
                                              int* __restrict__ adj_n,
                                              int* __restrict__ adj_e) {
    int e = blockIdx.x * 256 + threadIdx.x;
    if (e >= NEDGE) return;
    int s = src[e], h = he[e];
    int pn = off_n[s] + atomicAdd(&cur_n[s], 1);
    adj_n[pn] = h;
    int pe = off_e[h] + atomicAdd(&cur_e[h], 1);
    adj_e[pe] = s;
}

// ---------------- weights fp32 -> bf16 ----------------
__global__ __launch_bounds__(256) void k_cvt_w(const float* __restrict__ w1,
                                               const float* __restrict__ w2,
                                               unsigned short* __restrict__ o1,
                                               unsigned short* __restrict__ o2) {
    int t = blockIdx.x * 256 + threadIdx.x;
    const int n4 = DD * DD / 4;
    const float* s = (t < n4) ? w1 : w2;
    unsigned short* d = (t < n4) ? o1 : o2;
    int i = (t < n4) ? t : t - n4;
    float4 v = ((const float4*)s)[i];
    uint2 o;
    o.x = pack2(v.x, v.y);
    o.y = pack2(v.z, v.w);
    ((uint2*)d)[i] = o;
}

// ---------------- bf16 MFMA GEMM: C[m,n] = sum_k A[m,k]*W[n,k] ----------------
// Tile 64x128 (M x N), BK=32, 256 thr = 4 waves as 2x2; wave tile 32x64.
// 1564 blocks -> ~6 blocks/CU for latency hiding. Single-buffered LDS (12 KB),
// XOR swizzle: elem (row r, 8-elem seg s) at ushort offset r*32 + (s^(r&3))*8.
template <bool A32>
__global__ __launch_bounds__(256) void k_gemm_bf16(const void* __restrict__ Av,
                                                   const unsigned short* __restrict__ Wb,
                                                   unsigned short* __restrict__ Cb, int M) {
    __shared__ __align__(16) unsigned short As[64 * 32];
    __shared__ __align__(16) unsigned short Bs[128 * 32];
    const int t    = threadIdx.x;
    const int m0   = blockIdx.x * 64;
    const int n0   = blockIdx.y * 128;
    const int lane = t & 63;
    const int wave = t >> 6;
    const int wm   = (wave >> 1) * 32;
    const int wn   = (wave & 1) * 64;
    const int fr   = lane & 15;
    const int fq   = lane >> 4;

    f32x4 acc[2][4] = {};

    const int sr = t >> 2;   // staging row 0..63
    const int ss = t & 3;    // 8-elem k segment

    for (int k0 = 0; k0 < DD; k0 += 32) {
        // issue global loads first, then barrier (protect prior LDS reads)
        uint4 av = make_uint4(0u, 0u, 0u, 0u);
        {
            int gm = m0 + sr;
            if (gm < M) {
                if (A32) {
                    const float* p = (const float*)Av + (size_t)gm * DD + k0 + ss * 8;
                    float4 f0 = *(const float4*)p;
                    float4 f1 = *(const float4*)(p + 4);
                    av.x = pack2(f0.x, f0.y);
                    av.y = pack2(f0.z, f0.w);
                    av.z = pack2(f1.x, f1.y);
                    av.w = pack2(f1.z, f1.w);
                } else {
                    av = *(const uint4*)((const unsigned short*)Av + (size_t)gm * DD + k0 + ss * 8);
                }
            }
        }
        uint4 bv0 = *(const uint4*)(Wb + (size_t)(n0 + sr) * DD + k0 + ss * 8);
        uint4 bv1 = *(const uint4*)(Wb + (size_t)(n0 + sr + 64) * DD + k0 + ss * 8);
        __syncthreads();
        *(uint4*)(As + sr * 32 + ((ss ^ (sr & 3)) * 8)) = av;
        {
            int r0 = sr, r1 = sr + 64;
            *(uint4*)(Bs + r0 * 32 + ((ss ^ (r0 & 3)) * 8)) = bv0;
            *(uint4*)(Bs + r1 * 32 + ((ss ^ (r1 & 3)) * 8)) = bv1;
        }
        __syncthreads();

        short8 af[2], bf[4];
#pragma unroll
        for (int mt = 0; mt < 2; ++mt) {
            int r = wm + mt * 16 + fr;
            af[mt] = *(const short8*)(As + r * 32 + ((fq ^ (r & 3)) * 8));
        }
#pragma unroll
        for (int nt = 0; nt < 4; ++nt) {
            int r = wn + nt * 16 + fr;
            bf[nt] = *(const short8*)(Bs + r * 32 + ((fq ^ (r & 3)) * 8));
        }
#pragma unroll
        for (int mt = 0; mt < 2; ++mt)
#pragma unroll
            for (int nt = 0; nt < 4; ++nt)
                acc[mt][nt] = __builtin_amdgcn_mfma_f32_16x16x32_bf16(af[mt], bf[nt],
                                                                      acc[mt][nt], 0, 0, 0);
    }

    // C/D layout: col = lane&15, row = quad*4 + reg
#pragma unroll
    for (int mt = 0; mt < 2; ++mt) {
#pragma unroll
        for (int i = 0; i < 4; ++i) {
            int gm = m0 + wm + mt * 16 + fq * 4 + i;
            if (gm >= M) continue;
#pragma unroll
            for (int nt = 0; nt < 4; ++nt) {
                int gn = n0 + wn + nt * 16 + fr;
                Cb[(size_t)gm * DD + gn] = f2b(acc[mt][nt][i]);
            }
        }
    }
}

// ---------------- gather core: 32 lanes per row, uint4 (8 bf16) per lane ------
// unroll-8 neighbor batches (mean degree 6.4 -> one batch for most rows);
// clamped duplicate indices hit L1 (~free).
static __device__ __forceinline__ void acc8(float* a, uint4 v) {
    a[0] += b2f_lo(v.x); a[1] += b2f_hi(v.x);
    a[2] += b2f_lo(v.y); a[3] += b2f_hi(v.y);
    a[4] += b2f_lo(v.z); a[5] += b2f_hi(v.z);
    a[6] += b2f_lo(v.w); a[7] += b2f_hi(v.w);
}
static __device__ __forceinline__ void gather8(const unsigned short* __restrict__ srcb,
                                               const int* __restrict__ adj,
                                               int b, int e, int sl, float* a) {
#pragma unroll
    for (int i = 0; i < 8; ++i) a[i] = 0.f;
    for (int i = b; i < e; i += 8) {
        int g0 = adj[i];
        int g[8];
        g[0] = g0;
#pragma unroll
        for (int j = 1; j < 8; ++j) g[j] = (i + j < e) ? adj[i + j] : g0;
        uint4 v[8];
#pragma unroll
        for (int j = 0; j < 8; ++j)
            v[j] = *(const uint4*)(srcb + (size_t)g[j] * DD + sl * 8);
        acc8(a, v[0]);
#pragma unroll
        for (int j = 1; j < 8; ++j)
            if (i + j < e) acc8(a, v[j]);
    }
}

__global__ __launch_bounds__(256) void k_gather_edge_b(const unsigned short* __restrict__ xw,
                                                       unsigned short* __restrict__ ef,
                                                       const int* __restrict__ off,
                                                       const int* __restrict__ adj) {
    int tid = blockIdx.x * 256 + threadIdx.x;
    int w = tid >> 5;           // one 32-lane half-wave per row
    int sl = tid & 31;
    if (w >= NHE) return;
    int b = off[w], e = off[w + 1];
    float a[8];
    gather8(xw, adj, b, e, sl, a);
    float sc = (e > b) ? 1.f / (float)(e - b) : 0.f;
    uint4 o;
    o.x = pack2(a[0] * sc, a[1] * sc);
    o.y = pack2(a[2] * sc, a[3] * sc);
    o.z = pack2(a[4] * sc, a[5] * sc);
    o.w = pack2(a[6] * sc, a[7] * sc);
    *(uint4*)(ef + (size_t)w * DD + sl * 8) = o;
}

__global__ __launch_bounds__(256) void k_gather_node_mid_b(const unsigned short* __restrict__ ef,
                                                           unsigned short* __restrict__ h,
                                                           const int* __restrict__ off,
                                                           const int* __restrict__ adj,
                                                           const float* __restrict__ bias,
                                                           const float* __restrict__ aP) {
    int tid = blockIdx.x * 256 + threadIdx.x;
    int w = tid >> 5;
    int sl = tid & 31;
    if (w >= NN) return;
    int b = off[w], e = off[w + 1];
    float a[8];
    gather8(ef, adj, b, e, sl, a);
    float sc = (e > b) ? 1.f / (float)(e - b) : 0.f;
    float al = *aP;
    float4 bb0 = ((const float4*)bias)[sl * 2];
    float4 bb1 = ((const float4*)bias)[sl * 2 + 1];
    float r[8];
    r[0] = a[0] * sc + bb0.x; r[1] = a[1] * sc + bb0.y;
    r[2] = a[2] * sc + bb0.z; r[3] = a[3] * sc + bb0.w;
    r[4] = a[4] * sc + bb1.x; r[5] = a[5] * sc + bb1.y;
    r[6] = a[6] * sc + bb1.z; r[7] = a[7] * sc + bb1.w;
#pragma unroll
    for (int i = 0; i < 8; ++i) r[i] = (r[i] >= 0.f) ? r[i] : al * r[i];
    uint4 o;
    o.x = pack2(r[0], r[1]);
    o.y = pack2(r[2], r[3]);
    o.z = pack2(r[4], r[5]);
    o.w = pack2(r[6], r[7]);
    *(uint4*)(h + (size_t)w * DD + sl * 8) = o;
}

__global__ __launch_bounds__(256) void k_gather_node_final_b(const unsigned short* __restrict__ ef,
                                                             const float* __restrict__ x,
                                                             float* __restrict__ out,
                                                             const int* __restrict__ off,
                                                             const int* __restrict__ adj,
                                                             const float* __restrict__ bias,
                                                             const float* __restrict__ aP) {
    int tid = blockIdx.x * 256 + threadIdx.x;
    int w = tid >> 5;
    int sl = tid & 31;
    if (w >= NN) return;
    int b = off[w], e = off[w + 1];
    float a[8];
    gather8(ef, adj, b, e, sl, a);
    float sc = (e > b) ? 1.f / (float)(e - b) : 0.f;
    float al = *aP;
    float4 bb0 = ((const float4*)bias)[sl * 2];
    float4 bb1 = ((const float4*)bias)[sl * 2 + 1];
    const float* xp = x + (size_t)w * DD + sl * 8;
    float4 xv0 = *(const float4*)xp;
    float4 xv1 = *(const float4*)(xp + 4);
    float r[8];
    r[0] = a[0] * sc + bb0.x + xv0.x; r[1] = a[1] * sc + bb0.y + xv0.y;
    r[2] = a[2] * sc + bb0.z + xv0.z; r[3] = a[3] * sc + bb0.w + xv0.w;
    r[4] = a[4] * sc + bb1.x + xv1.x; r[5] = a[5] * sc + bb1.y + xv1.y;
    r[6] = a[6] * sc + bb1.z + xv1.z; r[7] = a[7] * sc + bb1.w + xv1.w;
#pragma unroll
    for (int i = 0; i < 8; ++i) r[i] = (r[i] >= 0.f) ? r[i] : al * r[i];
    float* op = out + (size_t)w * DD + sl * 8;
    *(float4*)op = make_float4(r[0], r[1], r[2], r[3]);
    *(float4*)(op + 4) = make_float4(r[4], r[5], r[6], r[7]);
}

extern "C" void kernel_launch(void* const* d_in, const int* in_sizes, int n_in,
                              void* d_out, int out_size, void* d_ws, size_t ws_size,
                              hipStream_t stream) {
    const float* x       = (const float*)d_in[0];
    const float* W1      = (const float*)d_in[1];
    const float* b1      = (const float*)d_in[2];
    const float* W2      = (const float*)d_in[3];
    const float* b2      = (const float*)d_in[4];
    const float* prelu_a = (const float*)d_in[5];
    const int*   hei     = (const int*)d_in[6];
    const int* idx_src = hei;          // hei[0,:] node indices
    const int* idx_he  = hei + NEDGE;  // hei[1,:] hyperedge indices

    float* out = (float*)d_out;
    unsigned short* B1 = (unsigned short*)d_ws;           // [NN*DD] bf16
    unsigned short* B2 = B1 + (size_t)NN * DD;            // [NN*DD] bf16
    int* off_n = (int*)(B2 + (size_t)NN * DD);            // NN+1
    int* off_e = off_n + NN + 1;                          // NHE+1
    int* cur_n = off_e + NHE + 1;                         // NN (counts)
    int* cur_e = cur_n + NN;                              // NHE
    int* adj_n = cur_e + NHE;                             // NEDGE
    int* adj_e = adj_n + NEDGE;                           // NEDGE
    int* bsum  = adj_e + NEDGE;                           // 2*NBLK
    int* bbase = bsum + 2 * NBLK;                         // 2*NBLK + 2
    // d_out doubles as bf16 weight storage until the final kernel
    unsigned short* w1b = (unsigned short*)d_out;         // [DD*DD]
    unsigned short* w2b = w1b + DD * DD;                  // [DD*DD]

    const int eblocks = (NEDGE + 255) / 256;
    const int gblocks = (NN * 32 + 255) / 256;            // 32 lanes per row
    dim3 ggrid((NN + 63) / 64, DD / 128);                 // 782 x 2 = 1564 blocks

    // ---- CSR build (parallel scan) ----
    hipMemsetAsync(cur_n, 0, sizeof(int) * (NN + NHE), stream);
    k_count<<<eblocks, 256, 0, stream>>>(idx_src, idx_he, cur_n, cur_e);
    k_scan_a<<<2 * NBLK, 256, 0, stream>>>(cur_n, cur_e, bsum);
    k_scan_b<<<1, 64, 0, stream>>>(bsum, bbase);
    k_scan_c<<<2 * NBLK, 256, 0, stream>>>(cur_n, cur_e, bbase, off_n, off_e);
    hipMemsetAsync(cur_n, 0, sizeof(int) * (NN + NHE), stream);
    k_fill<<<eblocks, 256, 0, stream>>>(idx_src, idx_he, off_n, off_e,
                                        cur_n, cur_e, adj_n, adj_e);

    // ---- weight conversions (x conversion fused into GEMM1) ----
    k_cvt_w<<<(2 * DD * DD / 4 + 255) / 256, 256, 0, stream>>>(W1, W2, w1b, w2b);

    // ---- layer 1 ----
    k_gemm_bf16<true><<<ggrid, 256, 0, stream>>>((const void*)x, w1b, B1, NN);   // B1 = bf16(x@W1^T)
    k_gather_edge_b<<<gblocks, 256, 0, stream>>>(B1, B2, off_e, adj_e);          // B2 = ef1
    k_gather_node_mid_b<<<gblocks, 256, 0, stream>>>(B2, B1, off_n, adj_n, b1, prelu_a); // B1 = h1

    // ---- layer 2 ----
    k_gemm_bf16<false><<<ggrid, 256, 0, stream>>>((const void*)B1, w2b, B2, NN); // B2 = bf16(h1@W2^T)
    k_gather_edge_b<<<gblocks, 256, 0, stream>>>(B2, B1, off_e, adj_e);          // B1 = ef2
    k_gather_node_final_b<<<gblocks, 256, 0, stream>>>(B1, x, out, off_n, adj_n, b2, prelu_a);
}